// Round 13
// baseline (221.475 us; speedup 1.0000x reference)
//
#include <hip/hip_runtime.h>

#define NN 8000
#define FD 256
#define NEG_SLOPE 0.2f
#define BM 32                 // i rows per block
#define KT 32                 // j per step
#define JS 4                  // j chunks: 2048,2048,2048,1856
#define WROW 40               // Wt row stride in bf16 (80 B, pad: <=2-way banks)

typedef __bf16 bf16;
typedef __bf16 bf16x8 __attribute__((ext_vector_type(8)));
typedef __bf16 bf16x4 __attribute__((ext_vector_type(4)));
typedef float f32x4 __attribute__((ext_vector_type(4)));

// ---------------- K1: H = X @ W^T + b -> Ht (bf16, [f][i]) ----------------
__global__ __launch_bounds__(256) void k_linear(const float* __restrict__ X,
                                                const float* __restrict__ W,
                                                const float* __restrict__ b,
                                                bf16* __restrict__ Ht) {
    __shared__ float Xs[16][260];
    const int t = threadIdx.x;
    const int i0 = blockIdx.x * 16;
    #pragma unroll
    for (int r = 0; r < 16; ++r)
        Xs[r][t] = X[(size_t)(i0 + r) * FD + t];
    __syncthreads();
    const int f = t;
    float acc[16];
    const float bf_ = b[f];
    #pragma unroll
    for (int ii = 0; ii < 16; ++ii) acc[ii] = bf_;
    for (int k4 = 0; k4 < FD / 4; ++k4) {
        const float4 w4 = *(const float4*)&W[(size_t)f * FD + k4 * 4];
        #pragma unroll
        for (int ii = 0; ii < 16; ++ii) {
            const float4 x4 = *(const float4*)&Xs[ii][k4 * 4];
            acc[ii] += x4.x * w4.x + x4.y * w4.y + x4.z * w4.z + x4.w * w4.w;
        }
    }
    bf16x8 v0, v1;
    #pragma unroll
    for (int ii = 0; ii < 8; ++ii) { v0[ii] = (bf16)acc[ii]; v1[ii] = (bf16)acc[ii + 8]; }
    *(bf16x8*)&Ht[(size_t)f * NN + i0]     = v0;
    *(bf16x8*)&Ht[(size_t)f * NN + i0 + 8] = v1;
}

// ---------------- K2: hs = H@a_src + a_b, hd = H@a_dst ----------------
__global__ __launch_bounds__(256) void k_attn_vec(const bf16* __restrict__ Ht,
                                                  const float* __restrict__ a_src,
                                                  const float* __restrict__ a_dst,
                                                  const float* __restrict__ a_b,
                                                  float* __restrict__ hs,
                                                  float* __restrict__ hd) {
    __shared__ float psh[4][64], pdh[4][64];
    const int t = threadIdx.x;
    const int li = t & 63;
    const int q = t >> 6;
    const int i = blockIdx.x * 64 + li;
    float ps = 0.f, pd = 0.f;
    #pragma unroll 8
    for (int fi = 0; fi < 64; ++fi) {
        const int f = q * 64 + fi;
        const float h = (float)Ht[(size_t)f * NN + i];
        ps += h * a_src[f];
        pd += h * a_dst[f];
    }
    psh[q][li] = ps; pdh[q][li] = pd;
    __syncthreads();
    if (q == 0) {
        ps = psh[0][li] + psh[1][li] + psh[2][li] + psh[3][li];
        pd = pdh[0][li] + pdh[1][li] + pdh[2][li] + pdh[3][li];
        hs[i] = ps + a_b[0];
        hd[i] = pd;
    }
}

// ---------------- K3: fused GAT, minimal LDS, 1 barrier/step ----------------
// 256 thr = 4 waves; block tile 32 i x 256 f; KT=32; grid 250 ib x 4 jb.
// Only the 32x32 weight tile (Wt, 80B-padded rows, ping-pong) lives in LDS.
// B (Ht frags) global->reg from L2; adj/hd 2-steps-deep in regs (32KB/CU in
// flight -> adj HBM stream saturates by Little's law). Wave wv owns 64 f cols;
// per step: 2 A ds_reads + 4 B L2 loads + 8 MFMA. Weights for s+1 computed
// between MFMA(s) issue and the single barrier.
__global__ __launch_bounds__(256, 4) void k_gat(const bf16* __restrict__ Ht,
                                                const int* __restrict__ adj,
                                                const float* __restrict__ hs,
                                                const float* __restrict__ hd,
                                                float* __restrict__ outP,
                                                float* __restrict__ lgP) {
    __shared__ __attribute__((aligned(16))) bf16 Wt[2][BM * WROW];  // 2 x 2560 B

    const int t  = threadIdx.x;
    const int l  = t & 63;
    const int wv = t >> 6;                 // col group: 64 f per wave
    const int jb = blockIdx.x / 250;
    const int ib = blockIdx.x % 250;
    const int i0 = ib * BM;
    const int j0 = jb * 2048;
    const int NS = (jb < 3) ? 64 : 58;     // 3*2048 + 58*32=1856 -> 8000

    // weight mapping: row r (8 thr/row), 4 j's at jm
    const int r  = t >> 3;
    const int jm = (t & 7) * 4;
    const float hsv = hs[i0 + r];
    const int*   adjp = adj + (size_t)(i0 + r) * NN + j0 + jm;
    const float* hdp  = hd + j0 + jm;
    char* const wby0 = (char*)&Wt[0][0] + r * (WROW * 2) + jm * 2;
    char* const wby1 = (char*)&Wt[1][0] + r * (WROW * 2) + jm * 2;

    // MFMA mapping
    const int al = l & 15, asl = l >> 4;
    const char* const a0p0 = (const char*)&Wt[0][0] + al * (WROW * 2) + asl * 16;
    const char* const a1p0 = (const char*)&Wt[0][0] + (16 + al) * (WROW * 2) + asl * 16;
    const char* const a0p1 = (const char*)&Wt[1][0] + al * (WROW * 2) + asl * 16;
    const char* const a1p1 = (const char*)&Wt[1][0] + (16 + al) * (WROW * 2) + asl * 16;
    const bf16* bp0 = Ht + (size_t)(wv * 64 + al) * NN + j0 + asl * 8;
    const bf16* bp1 = bp0 + (size_t)16 * NN;
    const bf16* bp2 = bp0 + (size_t)32 * NN;
    const bf16* bp3 = bp0 + (size_t)48 * NN;

    float lsum = 0.f;

    // weight compute helper (4 w's)
    auto wgen4 = [&](int4 aj, float4 hc) -> bf16x4 {
        float e, w0, w1, w2, w3;
        e = hsv + hc.x; e = fmaxf(e, NEG_SLOPE * e); w0 = aj.x ? __expf(e) : 0.f;
        e = hsv + hc.y; e = fmaxf(e, NEG_SLOPE * e); w1 = aj.y ? __expf(e) : 0.f;
        e = hsv + hc.z; e = fmaxf(e, NEG_SLOPE * e); w2 = aj.z ? __expf(e) : 0.f;
        e = hsv + hc.w; e = fmaxf(e, NEG_SLOPE * e); w3 = aj.w ? __expf(e) : 0.f;
        lsum += (w0 + w1) + (w2 + w3);
        bf16x4 w4; w4[0] = (bf16)w0; w4[1] = (bf16)w1; w4[2] = (bf16)w2; w4[3] = (bf16)w3;
        return w4;
    };

    // ---- prologue: weights(0) -> Wt[0]; load adj/hd(1); B(0) -> regs
    {
        const int4   aj0 = *(const int4*)adjp;
        const float4 hc0 = *(const float4*)hdp;
        *(bf16x4*)wby0 = wgen4(aj0, hc0);
    }
    int4   ajA = (NS > 1) ? *(const int4*)(adjp + KT) : (int4){0,0,0,0};
    float4 hdA = (NS > 1) ? *(const float4*)(hdp + KT) : (float4){0,0,0,0};
    bf16x8 bc0 = *(const bf16x8*)bp0;
    bf16x8 bc1 = *(const bf16x8*)bp1;
    bf16x8 bc2 = *(const bf16x8*)bp2;
    bf16x8 bc3 = *(const bf16x8*)bp3;
    __syncthreads();

    f32x4 acc[2][4];
    #pragma unroll
    for (int rg = 0; rg < 2; ++rg)
        #pragma unroll
        for (int cf = 0; cf < 4; ++cf) acc[rg][cf] = (f32x4){0.f, 0.f, 0.f, 0.f};

    #pragma unroll 1
    for (int s = 0; s < NS; ++s) {
        const int cur = s & 1;

        // issue B(s+1) (L2), then adj/hd(s+2) (HBM, stays in flight longest)
        bf16x8 bn0, bn1, bn2, bn3;
        if (s + 1 < NS) {
            bn0 = *(const bf16x8*)(bp0 + (size_t)(s + 1) * KT);
            bn1 = *(const bf16x8*)(bp1 + (size_t)(s + 1) * KT);
            bn2 = *(const bf16x8*)(bp2 + (size_t)(s + 1) * KT);
            bn3 = *(const bf16x8*)(bp3 + (size_t)(s + 1) * KT);
        }
        int4 ajB; float4 hdB;
        if (s + 2 < NS) {
            ajB = *(const int4*)(adjp + (size_t)(s + 2) * KT);
            hdB = *(const float4*)(hdp + (size_t)(s + 2) * KT);
        }

        // weights(s+1) -> other Wt buffer (uses regs loaded last step)
        if (s + 1 < NS) {
            const bf16x4 w4 = wgen4(ajA, hdA);
            *(bf16x4*)(cur ? wby0 : wby1) = w4;
        }

        // MFMA(s): A from Wt[cur], B from regs
        {
            const bf16x8 a0 = *(const bf16x8*)(cur ? a0p1 : a0p0);
            const bf16x8 a1 = *(const bf16x8*)(cur ? a1p1 : a1p0);
            acc[0][0] = __builtin_amdgcn_mfma_f32_16x16x32_bf16(a0, bc0, acc[0][0], 0, 0, 0);
            acc[0][1] = __builtin_amdgcn_mfma_f32_16x16x32_bf16(a0, bc1, acc[0][1], 0, 0, 0);
            acc[0][2] = __builtin_amdgcn_mfma_f32_16x16x32_bf16(a0, bc2, acc[0][2], 0, 0, 0);
            acc[0][3] = __builtin_amdgcn_mfma_f32_16x16x32_bf16(a0, bc3, acc[0][3], 0, 0, 0);
            acc[1][0] = __builtin_amdgcn_mfma_f32_16x16x32_bf16(a1, bc0, acc[1][0], 0, 0, 0);
            acc[1][1] = __builtin_amdgcn_mfma_f32_16x16x32_bf16(a1, bc1, acc[1][1], 0, 0, 0);
            acc[1][2] = __builtin_amdgcn_mfma_f32_16x16x32_bf16(a1, bc2, acc[1][2], 0, 0, 0);
            acc[1][3] = __builtin_amdgcn_mfma_f32_16x16x32_bf16(a1, bc3, acc[1][3], 0, 0, 0);
        }

        // rotate registers
        bc0 = bn0; bc1 = bn1; bc2 = bn2; bc3 = bn3;
        ajA = ajB; hdA = hdB;

        // own ds ops (Wt write + A reads) done, then single barrier
        asm volatile("s_waitcnt lgkmcnt(0)" ::: "memory");
        __builtin_amdgcn_s_barrier();
    }

    // ---- epilogue: per-chunk row sums (unique writer) + partial outputs
    lsum += __shfl_xor(lsum, 1);
    lsum += __shfl_xor(lsum, 2);
    lsum += __shfl_xor(lsum, 4);
    if ((t & 7) == 0) lgP[(size_t)jb * NN + i0 + r] = lsum;

    float* op = outP + (size_t)jb * NN * FD;
    #pragma unroll
    for (int rg = 0; rg < 2; ++rg)
        #pragma unroll
        for (int cf = 0; cf < 4; ++cf)
            #pragma unroll
            for (int g = 0; g < 4; ++g)
                op[(size_t)(i0 + rg * 16 + asl * 4 + g) * FD + wv * 64 + cf * 16 + al] =
                    acc[rg][cf][g];
}

// ---------------- K4: combine partials + normalize ----------------
__global__ __launch_bounds__(256) void k_norm(const float* __restrict__ outP,
                                              const float* __restrict__ lgP,
                                              float* __restrict__ out) {
    const int i = blockIdx.x;
    const int f = threadIdx.x;
    const float lsum = lgP[i] + lgP[NN + i] + lgP[2 * NN + i] + lgP[3 * NN + i];
    const size_t off = (size_t)i * FD + f;
    const size_t stride = (size_t)NN * FD;
    const float v = outP[off] + outP[stride + off] + outP[2 * stride + off]
                  + outP[3 * stride + off];
    out[off] = v * (1.0f / lsum);
}

extern "C" void kernel_launch(void* const* d_in, const int* in_sizes, int n_in,
                              void* d_out, int out_size, void* d_ws, size_t ws_size,
                              hipStream_t stream) {
    const float* X     = (const float*)d_in[0];
    const int*   adj   = (const int*)d_in[1];
    const float* Ww    = (const float*)d_in[2];
    const float* Wb    = (const float*)d_in[3];
    const float* a_src = (const float*)d_in[4];
    const float* a_dst = (const float*)d_in[5];
    const float* a_b   = (const float*)d_in[6];
    float* out = (float*)d_out;

    bf16*  Ht   = (bf16*)d_ws;                                // 4.096 MB
    float* hs   = (float*)((char*)d_ws + (size_t)FD * NN * sizeof(bf16));
    float* hd   = hs + NN;
    float* lgP  = hd + NN;                                    // 4 * NN
    float* outP = lgP + (size_t)JS * NN;                      // 4 * NN * FD = 32.8 MB

    k_linear<<<NN / 16, 256, 0, stream>>>(X, Ww, Wb, Ht);
    k_attn_vec<<<NN / 64, 256, 0, stream>>>(Ht, a_src, a_dst, a_b, hs, hd);
    k_gat<<<250 * JS, 256, 0, stream>>>(Ht, adj, hs, hd, outP, lgP);
    k_norm<<<NN, 256, 0, stream>>>(outP, lgP, out);
}

// Round 14
// 150.451 us; speedup vs baseline: 1.4721x; 1.4721x over previous
//
#include <hip/hip_runtime.h>

#define NN 8000
#define FD 256
#define NEG_SLOPE 0.2f
#define BM 64                 // i rows per block
#define KT 32                 // j per step
#define JCH 2048              // j chunk (last: 1856)

typedef __bf16 bf16;
typedef __bf16 bf16x8 __attribute__((ext_vector_type(8)));
typedef __bf16 bf16x4 __attribute__((ext_vector_type(4)));
typedef float f32x4 __attribute__((ext_vector_type(4)));

// ---------------- K1: H = X @ W^T + b -> Ht (bf16, [f][i]); zero out/lg ----
__global__ __launch_bounds__(256) void k_linear(const float* __restrict__ X,
                                                const float* __restrict__ W,
                                                const float* __restrict__ b,
                                                bf16* __restrict__ Ht,
                                                float* __restrict__ out,
                                                float* __restrict__ lg) {
    __shared__ float Xs[16][260];
    const int t = threadIdx.x;
    const int i0 = blockIdx.x * 16;
    {   // zero out (8 MB) + lg
        const int gt = blockIdx.x * 256 + t;
        const float4 z4 = {0.f, 0.f, 0.f, 0.f};
        float4* o4 = (float4*)out;
        #pragma unroll
        for (int k = 0; k < 4; ++k) o4[gt + k * 128000] = z4;
        if (gt < NN) lg[gt] = 0.f;
    }
    #pragma unroll
    for (int r = 0; r < 16; ++r)
        Xs[r][t] = X[(size_t)(i0 + r) * FD + t];
    __syncthreads();
    const int f = t;
    float acc[16];
    const float bf_ = b[f];
    #pragma unroll
    for (int ii = 0; ii < 16; ++ii) acc[ii] = bf_;
    for (int k4 = 0; k4 < FD / 4; ++k4) {
        const float4 w4 = *(const float4*)&W[(size_t)f * FD + k4 * 4];
        #pragma unroll
        for (int ii = 0; ii < 16; ++ii) {
            const float4 x4 = *(const float4*)&Xs[ii][k4 * 4];
            acc[ii] += x4.x * w4.x + x4.y * w4.y + x4.z * w4.z + x4.w * w4.w;
        }
    }
    bf16x8 v0, v1;
    #pragma unroll
    for (int ii = 0; ii < 8; ++ii) { v0[ii] = (bf16)acc[ii]; v1[ii] = (bf16)acc[ii + 8]; }
    *(bf16x8*)&Ht[(size_t)f * NN + i0]     = v0;
    *(bf16x8*)&Ht[(size_t)f * NN + i0 + 8] = v1;
}

// ---------------- K2: hs = H@a_src + a_b, hd = H@a_dst ----------------
__global__ __launch_bounds__(256) void k_attn_vec(const bf16* __restrict__ Ht,
                                                  const float* __restrict__ a_src,
                                                  const float* __restrict__ a_dst,
                                                  const float* __restrict__ a_b,
                                                  float* __restrict__ hs,
                                                  float* __restrict__ hd) {
    __shared__ float psh[4][64], pdh[4][64];
    const int t = threadIdx.x;
    const int li = t & 63;
    const int q = t >> 6;
    const int i = blockIdx.x * 64 + li;
    float ps = 0.f, pd = 0.f;
    #pragma unroll 8
    for (int fi = 0; fi < 64; ++fi) {
        const int f = q * 64 + fi;
        const float h = (float)Ht[(size_t)f * NN + i];
        ps += h * a_src[f];
        pd += h * a_dst[f];
    }
    psh[q][li] = ps; pdh[q][li] = pd;
    __syncthreads();
    if (q == 0) {
        ps = psh[0][li] + psh[1][li] + psh[2][li] + psh[3][li];
        pd = pdh[0][li] + pdh[1][li] + pdh[2][li] + pdh[3][li];
        hs[i] = ps + a_b[0];
        hd[i] = pd;
    }
}

// ---------------- K3: all-DMA fused GAT ----------------
// 512 thr = 8 waves (2 i-strips x 4 f-groups); BM=64, KT=32; grid 125 ib x 4 jb
// (jb = bid&3 -> one jb per XCD -> 1MB Ht slice L2-partitioned).
// ALL loop inputs arrive by global_load_lds DMA (adj: Adt[3], Ht: Bt[2]); hd
// staged once per block; weights via Wt[2] LDS. Exactly 3 DMA issues/thread/
// iter -> vmcnt(3) is exact; no register-held prefetch for the compiler to sink.
// Thread t DMA-writes and reads back ITS OWN 16B of Adt -> no barrier for adj.
__global__ __launch_bounds__(512, 2) void k_gat(const bf16* __restrict__ Ht,
                                                const int* __restrict__ adj,
                                                const float* __restrict__ hs,
                                                const float* __restrict__ hd,
                                                float* __restrict__ out,
                                                float* __restrict__ lg) {
    __shared__ __attribute__((aligned(16))) bf16 Bt[2][FD * KT];   // 2 x 16 KB
    __shared__ __attribute__((aligned(16))) int  Adt[3][BM * KT];  // 3 x 8 KB
    __shared__ __attribute__((aligned(16))) bf16 Wt[2][BM * 40];   // 2 x 5 KB (80B rows)
    __shared__ float hd_s[JCH];                                    // 8 KB

    const int t  = threadIdx.x;
    const int l  = t & 63;
    const int wv = t >> 6;
    const int jb = blockIdx.x & 3;
    const int ib = blockIdx.x >> 2;
    const int i0 = ib * BM;
    const int j0 = jb * JCH;
    const int NS = (jb < 3) ? 64 : 58;       // 3*2048 + 1856 = 8000

    // weight mapping: row r (0..63), jslot (0..7) -> 4 j's
    const int r  = t >> 3;
    const int js = t & 7;
    const float hsv = hs[i0 + r];

    // MFMA mapping: wave = (is, fg)
    const int is = wv >> 2, fg = wv & 3;
    const int al = l & 15, asl = l >> 4;
    const int bswz = (asl ^ ((al >> 2) & 3)) << 4;   // Bt read slot byte offset

    auto stage_bt = [&](int s_, int buf) {
        #pragma unroll
        for (int q = 0; q < 2; ++q) {
            const int idx = q * 512 + t;
            const int col = idx >> 2, ks = idx & 3;
            const bf16* src = Ht + (size_t)col * NN + j0 + s_ * KT
                              + ((ks ^ ((col >> 2) & 3)) * 8);
            bf16* dst = &Bt[buf][idx * 8];
            __builtin_amdgcn_global_load_lds(
                (const __attribute__((address_space(1))) void*)src,
                (__attribute__((address_space(3))) void*)dst, 16, 0, 0);
        }
    };
    auto stage_ad = [&](int s_, int buf) {
        const int* src = adj + (size_t)(i0 + r) * NN + j0 + s_ * KT + js * 4;
        int* dst = &Adt[buf][t * 4];    // linear: row r*32 + js*4 == t*4
        __builtin_amdgcn_global_load_lds(
            (const __attribute__((address_space(1))) void*)src,
            (__attribute__((address_space(3))) void*)dst, 16, 0, 0);
    };

    // ---- prologue: DMA Ad(0),Ad(1),Bt(0); stage hd chunk + zero-pad
    stage_ad(0, 0);
    stage_ad(1, 1);
    stage_bt(0, 0);
    {
        const int jg = j0 + t * 4;
        float4 h4 = {0.f, 0.f, 0.f, 0.f};
        if (jg + 3 < NN) h4 = *(const float4*)(hd + jg);
        *(float4*)&hd_s[t * 4] = h4;
    }
    asm volatile("s_waitcnt lgkmcnt(0)" ::: "memory");
    __builtin_amdgcn_s_barrier();

    f32x4 acc[2][4];
    #pragma unroll
    for (int rb = 0; rb < 2; ++rb)
        #pragma unroll
        for (int cf = 0; cf < 4; ++cf) acc[rb][cf] = (f32x4){0.f, 0.f, 0.f, 0.f};
    float lsum = 0.f;

    #pragma unroll 1
    for (int s = 0; s < NS; ++s) {
        const int bt = s & 1;
        // 1) issue next DMAs (the ONLY VM ops in the loop)
        if (s + 1 < NS) stage_bt(s + 1, (s + 1) & 1);
        if (s + 2 < NS) stage_ad(s + 2, (s + 2) % 3);
        // 2) counted drain: everything older than this iter's issues
        if (s + 2 < NS)      asm volatile("s_waitcnt vmcnt(3)" ::: "memory");
        else if (s + 1 < NS) asm volatile("s_waitcnt vmcnt(2)" ::: "memory");
        else                 asm volatile("s_waitcnt vmcnt(0)" ::: "memory");

        // 3) weight phase: own 16B of Adt + hd_s broadcast; 4 exps -> Wt
        {
            const int4 a4 = *(const int4*)&Adt[s % 3][t * 4];
            const float4 h4 = *(const float4*)&hd_s[s * KT + js * 4];
            float e, w0, w1, w2, w3;
            e = hsv + h4.x; e = fmaxf(e, NEG_SLOPE * e); w0 = a4.x ? __expf(e) : 0.f;
            e = hsv + h4.y; e = fmaxf(e, NEG_SLOPE * e); w1 = a4.y ? __expf(e) : 0.f;
            e = hsv + h4.z; e = fmaxf(e, NEG_SLOPE * e); w2 = a4.z ? __expf(e) : 0.f;
            e = hsv + h4.w; e = fmaxf(e, NEG_SLOPE * e); w3 = a4.w ? __expf(e) : 0.f;
            lsum += (w0 + w1) + (w2 + w3);
            bf16x4 w4v;
            w4v[0] = (bf16)w0; w4v[1] = (bf16)w1; w4v[2] = (bf16)w2; w4v[3] = (bf16)w3;
            *(bf16x4*)((char*)&Wt[bt][0] + r * 80 + js * 8) = w4v;
        }
        asm volatile("s_waitcnt lgkmcnt(0)" ::: "memory");
        __builtin_amdgcn_s_barrier();

        // 4) MFMA phase: A from Wt (padded rows), B from Bt (slot-XOR)
        {
            const char* Ab = (const char*)&Wt[bt][0];
            const char* Bb = (const char*)&Bt[bt][0];
            bf16x8 a[2], b[4];
            #pragma unroll
            for (int rb = 0; rb < 2; ++rb)
                a[rb] = *(const bf16x8*)(Ab + (is * 32 + rb * 16 + al) * 80 + asl * 16);
            #pragma unroll
            for (int cf = 0; cf < 4; ++cf)
                b[cf] = *(const bf16x8*)(Bb + (fg * 64 + cf * 16 + al) * 64 + bswz);
            #pragma unroll
            for (int rb = 0; rb < 2; ++rb)
                #pragma unroll
                for (int cf = 0; cf < 4; ++cf)
                    acc[rb][cf] = __builtin_amdgcn_mfma_f32_16x16x32_bf16(
                        a[rb], b[cf], acc[rb][cf], 0, 0, 0);
        }
        asm volatile("s_waitcnt lgkmcnt(0)" ::: "memory");
        __builtin_amdgcn_s_barrier();
    }

    // ---- epilogue: row sums (8 threads share row r) + atomic numerator
    lsum += __shfl_xor(lsum, 1);
    lsum += __shfl_xor(lsum, 2);
    lsum += __shfl_xor(lsum, 4);
    if ((t & 7) == 0) atomicAdd(&lg[i0 + r], lsum);

    #pragma unroll
    for (int rb = 0; rb < 2; ++rb)
        #pragma unroll
        for (int cf = 0; cf < 4; ++cf)
            #pragma unroll
            for (int g = 0; g < 4; ++g)
                atomicAdd(&out[(size_t)(i0 + is * 32 + rb * 16 + asl * 4 + g) * FD
                               + fg * 64 + cf * 16 + al], acc[rb][cf][g]);
}

// ---------------- K4: normalize by row sums ----------------
__global__ __launch_bounds__(256) void k_norm(float* __restrict__ out,
                                              const float* __restrict__ lg) {
    const int i = blockIdx.x;
    const float rinv = 1.0f / lg[i];
    out[(size_t)i * FD + threadIdx.x] *= rinv;
}

extern "C" void kernel_launch(void* const* d_in, const int* in_sizes, int n_in,
                              void* d_out, int out_size, void* d_ws, size_t ws_size,
                              hipStream_t stream) {
    const float* X     = (const float*)d_in[0];
    const int*   adj   = (const int*)d_in[1];
    const float* Ww    = (const float*)d_in[2];
    const float* Wb    = (const float*)d_in[3];
    const float* a_src = (const float*)d_in[4];
    const float* a_dst = (const float*)d_in[5];
    const float* a_b   = (const float*)d_in[6];
    float* out = (float*)d_out;

    bf16*  Ht = (bf16*)d_ws;                                  // 4.096 MB
    float* hs = (float*)((char*)d_ws + (size_t)FD * NN * sizeof(bf16));
    float* hd = hs + NN;
    float* lg = hd + NN;

    k_linear<<<NN / 16, 256, 0, stream>>>(X, Ww, Wb, Ht, out, lg);
    k_attn_vec<<<NN / 64, 256, 0, stream>>>(Ht, a_src, a_dst, a_b, hs, hd);
    k_gat<<<125 * 4, 512, 0, stream>>>(Ht, adj, hs, hd, out, lg);
    k_norm<<<NN, 256, 0, stream>>>(out, lg);
}